// Round 8
// baseline (148.528 us; speedup 1.0000x reference)
//
#include <hip/hip_runtime.h>

#define KK 4
#define BATCH 32768
#define NN 10
#define GPW 12           // graphs per wave: 12 b's; 5 lanes/graph, 2 nodes/lane
#define SLAB 132         // dwords per graph slab; 132 % 32 = 4 -> 2-way max on slab spread
#define NTHREADS 256     // 4 waves; wave w == k index

static constexpr size_t OFF_AIK = (size_t)KK * BATCH * NN * NN;           // 13107200
static constexpr size_t OFF_TJ  = OFF_AIK + (size_t)KK * BATCH * NN;      // 14417920
static constexpr size_t OFF_R   = OFF_TJ  + (size_t)KK * BATCH * NN;      // 15728640
static constexpr size_t OFF_RT  = OFF_R   + (size_t)KK * BATCH * NN * NN; // 28835840

// slab layout (dwords):
//   [0..100)   wt transpose (early); h/y2 exchange rows at n*12 [0..120);
//              ky rows at n*10 [0..100) (head phase)
//   [120..130) dinv (early) then t_k logits (head phase)
#define WSYNC() do { asm volatile("" ::: "memory"); \
                     __builtin_amdgcn_wave_barrier(); \
                     asm volatile("" ::: "memory"); } while (0)

__device__ __forceinline__ float rcpf(float x) {
#if __has_builtin(__builtin_amdgcn_rcpf)
    return __builtin_amdgcn_rcpf(x);
#else
    return 1.f / x;
#endif
}
__device__ __forceinline__ float fexp2(float x) {
#if __has_builtin(__builtin_amdgcn_exp2f)
    return __builtin_amdgcn_exp2f(x);
#else
    return exp2f(x);
#endif
}

// ---- packed fp32 helpers (VOP3P; add/mul/fma only on gfx950). Bit-exact IEEE fp32.
//      All validated numerically in rounds 5/7. ----
static __device__ __forceinline__ float2 pk_mul2(float2 a, float2 b) {
    float2 d; asm("v_pk_mul_f32 %0, %1, %2" : "=v"(d) : "v"(a), "v"(b)); return d; }
static __device__ __forceinline__ float2 pk_fma2(float2 a, float2 b, float2 c) {
    float2 d; asm("v_pk_fma_f32 %0, %1, %2, %3" : "=v"(d) : "v"(a), "v"(b), "v"(c)); return d; }
static __device__ __forceinline__ float2 pk_fma_blo(float2 a, float2 b, float2 c) {
    float2 d; asm("v_pk_fma_f32 %0, %1, %2, %3 op_sel_hi:[0,1,1]"
                  : "=v"(d) : "v"(a), "v"(b), "v"(c)); return d; }
static __device__ __forceinline__ float2 pk_fma_bhi(float2 a, float2 b, float2 c) {
    float2 d; asm("v_pk_fma_f32 %0, %1, %2, %3 op_sel:[1,0,0] op_sel_hi:[1,1,1]"
                  : "=v"(d) : "v"(a), "v"(b), "v"(c)); return d; }
static __device__ __forceinline__ float2 pk_fma_blo_s(float2 a, float2 bs, float2 c) {
    float2 d; asm("v_pk_fma_f32 %0, %1, %2, %3 op_sel_hi:[0,1,1]"
                  : "=v"(d) : "v"(a), "s"(bs), "v"(c)); return d; }
static __device__ __forceinline__ float2 pk_fma_bhi_s(float2 a, float2 bs, float2 c) {
    float2 d; asm("v_pk_fma_f32 %0, %1, %2, %3 op_sel:[1,0,0] op_sel_hi:[1,1,1]"
                  : "=v"(d) : "v"(a), "s"(bs), "v"(c)); return d; }
static __device__ __forceinline__ float2 pk_mul_blo_s(float2 a, float2 bs) {
    float2 d; asm("v_pk_mul_f32 %0, %1, %2 op_sel_hi:[0,1]"
                  : "=v"(d) : "v"(a), "s"(bs)); return d; }
static __device__ __forceinline__ float2 pk_fma_vs(float2 a, float2 bs, float2 c) {
    float2 d; asm("v_pk_fma_f32 %0, %1, %2, %3" : "=v"(d) : "v"(a), "s"(bs), "v"(c)); return d; }
static __device__ __forceinline__ float2 pk_add_vs(float2 a, float2 bs) {
    float2 d; asm("v_pk_add_f32 %0, %1, %2" : "=v"(d) : "v"(a), "s"(bs)); return d; }
static __device__ __forceinline__ float2 leaky2(float2 v) {
    return make_float2(fmaxf(v.x, 0.f) + 0.01f * fminf(v.x, 0.f),
                       fmaxf(v.y, 0.f) + 0.01f * fminf(v.y, 0.f)); }

__global__ __launch_bounds__(NTHREADS, 4)
void gnn_fused(const float* __restrict__ xin,
               const float* __restrict__ ew,
               const float* __restrict__ eigen,
               const float* __restrict__ a0p,
               const float* __restrict__ W0p,
               const float* __restrict__ b0p,
               const float* __restrict__ W1p,
               const float* __restrict__ b1p,
               const float* __restrict__ bpp,
               const float* __restrict__ cpp,
               const float* __restrict__ wwp,
               float* __restrict__ out)
{
    __shared__ __align__(16) float sm[KK * GPW * SLAB];   // 25,344 B

    const float LOG2E = 1.4426950408889634f;
    const float2 zero2 = make_float2(0.f, 0.f);

    const int t = threadIdx.x;
    const int l = t & 63;
    const int w = t >> 6;             // k index
    int gg = l / 5;                   // graph slot 0..12
    const int t5 = l - gg * 5;        // 0..4 (lanes 60..63 -> t5 0..3)
    if (gg > 11) gg = 11;             // dup lanes mirror graph 11 (identical writes)
    const int n0 = 2 * t5, n1 = n0 + 1;
    const int bb = blockIdx.x * GPW + gg;
    const bool valid = (l < 60) && (bb < BATCH);
    const int bbc = (bb < BATCH) ? bb : (BATCH - 1);
    const int g   = w * BATCH + bbc;

    float* slab = sm + (w * GPW + gg) * SLAB;

    // ---- own two outgoing edge-weight rows DIRECT from global (18 floats, 8B-aligned) ----
    float rw[18];
    {
        const float* rp = ew + (size_t)g * 90 + n0 * 9;
#pragma unroll
        for (int i = 0; i < 9; ++i) {
            float2 v = *(const float2*)(rp + 2 * i);
            rw[2*i] = v.x; rw[2*i+1] = v.y;
        }
    }
    const float* xb = xin + ((size_t)g * 10 + n0) * 3;   // 6 floats, 8B-aligned
    const float2 f0 = *(const float2*)(xb);
    const float2 f1 = *(const float2*)(xb + 2);
    const float2 f2 = *(const float2*)(xb + 4);
    // node A: (f0.x, f0.y, f1.x)   node B: (f1.y, f2.x, f2.y)
    const float eig = eigen[g];
    const float a0v = a0p[0];
    const float2 eig2 = make_float2(eig, eig);

    // ---- wout for both nodes ----
    float wA[10], wB[10];
#pragma unroll
    for (int j = 0; j < 10; ++j) {
        wA[j] = (j == n0) ? 0.f : ((j < n0) ? rw[j]     : rw[j-1]);
        wB[j] = (j == n1) ? 0.f : ((j < n1) ? rw[9+j]   : rw[8+j]);
    }

    // ---- R rows (2 rows = 20 floats, 16B-aligned float4 stores) ----
    if (valid) {
        float* pr = out + OFF_R + (size_t)g * 100 + n0 * 10;
        float2 m0 = pk_mul2(make_float2(wA[0], wA[1]), eig2);
        float2 m1 = pk_mul2(make_float2(wA[2], wA[3]), eig2);
        float2 m2 = pk_mul2(make_float2(wA[4], wA[5]), eig2);
        float2 m3 = pk_mul2(make_float2(wA[6], wA[7]), eig2);
        float2 m4 = pk_mul2(make_float2(wA[8], wA[9]), eig2);
        float2 m5 = pk_mul2(make_float2(wB[0], wB[1]), eig2);
        float2 m6 = pk_mul2(make_float2(wB[2], wB[3]), eig2);
        float2 m7 = pk_mul2(make_float2(wB[4], wB[5]), eig2);
        float2 m8 = pk_mul2(make_float2(wB[6], wB[7]), eig2);
        float2 m9 = pk_mul2(make_float2(wB[8], wB[9]), eig2);
        *(float4*)(pr +  0) = make_float4(m0.x, m0.y, m1.x, m1.y);
        *(float4*)(pr +  4) = make_float4(m2.x, m2.y, m3.x, m3.y);
        *(float4*)(pr +  8) = make_float4(m4.x, m4.y, m5.x, m5.y);
        *(float4*)(pr + 12) = make_float4(m6.x, m6.y, m7.x, m7.y);
        *(float4*)(pr + 16) = make_float4(m8.x, m8.y, m9.x, m9.y);
    }

    // ---- transpose through LDS: wt[j][n] = w(n->j); rows n are incoming rows ----
#pragma unroll
    for (int j = 0; j < 10; ++j)
        *(float2*)(slab + j * 10 + n0) = make_float2(wA[j], wB[j]);
    WSYNC();
    float inA[10], inB[10];
    {
        const float* rp = slab + n0 * 10;     // 20 contiguous floats, 16B-aligned
#pragma unroll
        for (int q = 0; q < 5; ++q) {
            float4 v = *(const float4*)(rp + 4 * q);
            const int i = 4 * q;
            ((i+0 < 10) ? inA[i+0]   : inB[i-10])   = v.x;
            ((i+1 < 10) ? inA[(i+1)%10] : inB[i-9]) = v.y;
            ((i+2 < 10) ? inA[(i+2)%10] : inB[i-8]) = v.z;
            ((i+3 < 10) ? inA[(i+3)%10] : inB[i-7]) = v.w;
        }
    }
    float degA = 0.f, degB = 0.f;
#pragma unroll
    for (int m = 0; m < 10; ++m) { degA += inA[m]; degB += inB[m]; }

    // ---- R_t rows ----
    if (valid) {
        float* pt = out + OFF_RT + (size_t)g * 100 + n0 * 10;
        float2 m0 = pk_mul2(make_float2(inA[0], inA[1]), eig2);
        float2 m1 = pk_mul2(make_float2(inA[2], inA[3]), eig2);
        float2 m2 = pk_mul2(make_float2(inA[4], inA[5]), eig2);
        float2 m3 = pk_mul2(make_float2(inA[6], inA[7]), eig2);
        float2 m4 = pk_mul2(make_float2(inA[8], inA[9]), eig2);
        float2 m5 = pk_mul2(make_float2(inB[0], inB[1]), eig2);
        float2 m6 = pk_mul2(make_float2(inB[2], inB[3]), eig2);
        float2 m7 = pk_mul2(make_float2(inB[4], inB[5]), eig2);
        float2 m8 = pk_mul2(make_float2(inB[6], inB[7]), eig2);
        float2 m9 = pk_mul2(make_float2(inB[8], inB[9]), eig2);
        *(float4*)(pt +  0) = make_float4(m0.x, m0.y, m1.x, m1.y);
        *(float4*)(pt +  4) = make_float4(m2.x, m2.y, m3.x, m3.y);
        *(float4*)(pt +  8) = make_float4(m4.x, m4.y, m5.x, m5.y);
        *(float4*)(pt + 12) = make_float4(m6.x, m6.y, m7.x, m7.y);
        *(float4*)(pt + 16) = make_float4(m8.x, m8.y, m9.x, m9.y);
    }

    // ---- dinv exchange ----
    const float dvA = (degA > 0.f) ? __frsqrt_rn(degA) : 0.f;
    const float dvB = (degB > 0.f) ? __frsqrt_rn(degB) : 0.f;
    *(float2*)(slab + 120 + n0) = make_float2(dvA, dvB);
    WSYNC();
    float2 arA[5], arB[5];
    {
        float dinv[10];
        float4 da = *(const float4*)(slab + 120);
        float4 db = *(const float4*)(slab + 124);
        float2 dc = *(const float2*)(slab + 128);
        dinv[0]=da.x; dinv[1]=da.y; dinv[2]=da.z; dinv[3]=da.w;
        dinv[4]=db.x; dinv[5]=db.y; dinv[6]=db.z; dinv[7]=db.w;
        dinv[8]=dc.x; dinv[9]=dc.y;
        const float2 dvA2 = make_float2(dvA, dvA);
        const float2 dvB2 = make_float2(dvB, dvB);
#pragma unroll
        for (int q = 0; q < 5; ++q) {
            const float2 dq = make_float2(dinv[2*q], dinv[2*q+1]);
            arA[q] = pk_mul2(pk_mul2(dq, make_float2(inA[2*q], inA[2*q+1])), dvA2);
            arB[q] = pk_mul2(pk_mul2(dq, make_float2(inB[2*q], inB[2*q+1])), dvB2);
        }
    }

    // ================= TAGConv layer 0: 3 -> 16, feature-packed, 2 nodes =================
    float2 habA = make_float2(f0.x, f0.y), hcjA = make_float2(f1.x, 0.f);
    float2 habB = make_float2(f1.y, f2.x), hcjB = make_float2(f2.y, 0.f);
    const float x2A = f1.x, x2B = f2.y;
    float2 accA0[8], accB0[8];
#pragma unroll
    for (int q = 0; q < 8; ++q) {
        float2 wa = *(const float2*)(W0p + 2*q);
        float2 wb = *(const float2*)(W0p + 16 + 2*q);
        float2 wc = *(const float2*)(W0p + 32 + 2*q);
        accA0[q] = pk_mul_blo_s(habA, wa);
        accA0[q] = pk_fma_bhi_s(habA, wb, accA0[q]);
        accA0[q] = pk_fma_blo_s(hcjA, wc, accA0[q]);
        accB0[q] = pk_mul_blo_s(habB, wa);
        accB0[q] = pk_fma_bhi_s(habB, wb, accB0[q]);
        accB0[q] = pk_fma_blo_s(hcjB, wc, accB0[q]);
    }
#pragma unroll
    for (int hop = 1; hop <= 3; ++hop) {
        *(float4*)(slab + n0 * 12) = make_float4(habA.x, habA.y, hcjA.x, hcjA.y);
        *(float4*)(slab + n1 * 12) = make_float4(habB.x, habB.y, hcjB.x, hcjB.y);
        WSYNC();
        float2 nabA = zero2, ncjA = zero2, nabB = zero2, ncjB = zero2;
#pragma unroll
        for (int m = 0; m < 10; ++m) {
            const float4 hm = *(const float4*)(slab + m * 12);
            const float2 hx = make_float2(hm.x, hm.y);
            const float2 hz = make_float2(hm.z, hm.w);
            const float2 aAm = arA[m >> 1], aBm = arB[m >> 1];
            if ((m & 1) == 0) {
                nabA = pk_fma_blo(aAm, hx, nabA); ncjA = pk_fma_blo(aAm, hz, ncjA);
                nabB = pk_fma_blo(aBm, hx, nabB); ncjB = pk_fma_blo(aBm, hz, ncjB);
            } else {
                nabA = pk_fma_bhi(aAm, hx, nabA); ncjA = pk_fma_bhi(aAm, hz, ncjA);
                nabB = pk_fma_bhi(aBm, hx, nabB); ncjB = pk_fma_bhi(aBm, hz, ncjB);
            }
        }
        WSYNC();
#pragma unroll
        for (int q = 0; q < 8; ++q) {
            float2 wa = *(const float2*)(W0p + hop*48 + 2*q);
            float2 wb = *(const float2*)(W0p + hop*48 + 16 + 2*q);
            float2 wc = *(const float2*)(W0p + hop*48 + 32 + 2*q);
            accA0[q] = pk_fma_blo_s(nabA, wa, accA0[q]);
            accA0[q] = pk_fma_bhi_s(nabA, wb, accA0[q]);
            accA0[q] = pk_fma_blo_s(ncjA, wc, accA0[q]);
            accB0[q] = pk_fma_blo_s(nabB, wa, accB0[q]);
            accB0[q] = pk_fma_bhi_s(nabB, wb, accB0[q]);
            accB0[q] = pk_fma_blo_s(ncjB, wc, accB0[q]);
        }
        habA = nabA; hcjA = ncjA; habB = nabB; hcjB = ncjB;
    }
    float2 y1A[8], y1B[8];
#pragma unroll
    for (int q = 0; q < 8; ++q) {
        float2 b2 = *(const float2*)(b0p + 2*q);
        y1A[q] = leaky2(pk_add_vs(accA0[q], b2));
        y1B[q] = leaky2(pk_add_vs(accB0[q], b2));
    }

    // ===== TAGConv layer 1: 16 -> 8, Horner, feature-packed, 2 nodes =====
    float2 curA[4], curB[4];
#pragma unroll
    for (int q = 0; q < 4; ++q) {
        float2 w0 = *(const float2*)(W1p + 384 + 2*q);
        curA[q] = pk_mul_blo_s(y1A[0], w0);
        curB[q] = pk_mul_blo_s(y1B[0], w0);
        float2 w1 = *(const float2*)(W1p + 384 + 8 + 2*q);
        curA[q] = pk_fma_bhi_s(y1A[0], w1, curA[q]);
        curB[q] = pk_fma_bhi_s(y1B[0], w1, curB[q]);
#pragma unroll
        for (int p8 = 1; p8 < 8; ++p8) {
            float2 wl = *(const float2*)(W1p + 384 + (2*p8)*8 + 2*q);
            float2 wh = *(const float2*)(W1p + 384 + (2*p8+1)*8 + 2*q);
            curA[q] = pk_fma_blo_s(y1A[p8], wl, curA[q]);
            curA[q] = pk_fma_bhi_s(y1A[p8], wh, curA[q]);
            curB[q] = pk_fma_blo_s(y1B[p8], wl, curB[q]);
            curB[q] = pk_fma_bhi_s(y1B[p8], wh, curB[q]);
        }
    }
#pragma unroll
    for (int kh = 2; kh >= 0; --kh) {
        *(float4*)(slab + n0 * 12)     = make_float4(curA[0].x, curA[0].y, curA[1].x, curA[1].y);
        *(float4*)(slab + n0 * 12 + 4) = make_float4(curA[2].x, curA[2].y, curA[3].x, curA[3].y);
        *(float4*)(slab + n1 * 12)     = make_float4(curB[0].x, curB[0].y, curB[1].x, curB[1].y);
        *(float4*)(slab + n1 * 12 + 4) = make_float4(curB[2].x, curB[2].y, curB[3].x, curB[3].y);
        WSYNC();
        float2 agA[4] = {zero2, zero2, zero2, zero2};
        float2 agB[4] = {zero2, zero2, zero2, zero2};
#pragma unroll
        for (int m = 0; m < 10; ++m) {
            const float4 p = *(const float4*)(slab + m * 12);
            const float4 r = *(const float4*)(slab + m * 12 + 4);
            const float2 pa = make_float2(p.x, p.y), pb = make_float2(p.z, p.w);
            const float2 ra = make_float2(r.x, r.y), rb = make_float2(r.z, r.w);
            const float2 aAm = arA[m >> 1], aBm = arB[m >> 1];
            if ((m & 1) == 0) {
                agA[0] = pk_fma_blo(aAm, pa, agA[0]); agA[1] = pk_fma_blo(aAm, pb, agA[1]);
                agA[2] = pk_fma_blo(aAm, ra, agA[2]); agA[3] = pk_fma_blo(aAm, rb, agA[3]);
                agB[0] = pk_fma_blo(aBm, pa, agB[0]); agB[1] = pk_fma_blo(aBm, pb, agB[1]);
                agB[2] = pk_fma_blo(aBm, ra, agB[2]); agB[3] = pk_fma_blo(aBm, rb, agB[3]);
            } else {
                agA[0] = pk_fma_bhi(aAm, pa, agA[0]); agA[1] = pk_fma_bhi(aAm, pb, agA[1]);
                agA[2] = pk_fma_bhi(aAm, ra, agA[2]); agA[3] = pk_fma_bhi(aAm, rb, agA[3]);
                agB[0] = pk_fma_bhi(aBm, pa, agB[0]); agB[1] = pk_fma_bhi(aBm, pb, agB[1]);
                agB[2] = pk_fma_bhi(aBm, ra, agB[2]); agB[3] = pk_fma_bhi(aBm, rb, agB[3]);
            }
        }
        WSYNC();
#pragma unroll
        for (int q = 0; q < 4; ++q) {
            curA[q] = agA[q]; curB[q] = agB[q];
#pragma unroll
            for (int p8 = 0; p8 < 8; ++p8) {
                float2 wl = *(const float2*)(W1p + kh*128 + (2*p8)*8 + 2*q);
                float2 wh = *(const float2*)(W1p + kh*128 + (2*p8+1)*8 + 2*q);
                curA[q] = pk_fma_blo_s(y1A[p8], wl, curA[q]);
                curA[q] = pk_fma_bhi_s(y1A[p8], wh, curA[q]);
                curB[q] = pk_fma_blo_s(y1B[p8], wl, curB[q]);
                curB[q] = pk_fma_bhi_s(y1B[p8], wh, curB[q]);
            }
        }
    }
    float2 y2A[4], y2B[4];
#pragma unroll
    for (int q = 0; q < 4; ++q) {
        float2 b2 = *(const float2*)(b1p + 2*q);
        y2A[q] = leaky2(pk_add_vs(curA[q], b2));
        y2B[q] = leaky2(pk_add_vs(curB[q], b2));
    }

    // ================= heads =================
    *(float4*)(slab + n0 * 12)     = make_float4(y2A[0].x, y2A[0].y, y2A[1].x, y2A[1].y);
    *(float4*)(slab + n0 * 12 + 4) = make_float4(y2A[2].x, y2A[2].y, y2A[3].x, y2A[3].y);
    *(float4*)(slab + n1 * 12)     = make_float4(y2B[0].x, y2B[0].y, y2B[1].x, y2B[1].y);
    *(float4*)(slab + n1 * 12 + 4) = make_float4(y2B[2].x, y2B[2].y, y2B[3].x, y2B[3].y);

    float2 aaA = zero2, aaB = zero2, ttA = zero2, ttB = zero2;
#pragma unroll
    for (int q = 0; q < 4; ++q) {
        float2 bp2 = *(const float2*)(bpp + 2*q);
        float2 cp2 = *(const float2*)(cpp + 2*q);
        aaA = pk_fma_vs(y2A[q], bp2, aaA);
        aaB = pk_fma_vs(y2B[q], bp2, aaB);
        ttA = pk_fma_vs(y2A[q], cp2, ttA);
        ttB = pk_fma_vs(y2B[q], cp2, ttB);
    }
    if (valid)
        *(float2*)(out + OFF_AIK + (size_t)g * 10 + n0) =
            make_float2(a0v + fmaxf(aaA.x + aaA.y, 0.f), a0v + fmaxf(aaB.x + aaB.y, 0.f));

    float tkA = (ttA.x + ttA.y) * (1.f - fmaxf(x2A, 0.f));
    float tkB = (ttB.x + ttB.y) * (1.f - fmaxf(x2B, 0.f));
    if (tkA == 0.f) tkA = -1e10f;
    if (tkB == 0.f) tkB = -1e10f;
    const float2 tks = make_float2(tkA * LOG2E, tkB * LOG2E);

    float2 ywA[4], ywB[4];   // (yw[2qd], yw[2qd+1]) per node
#pragma unroll
    for (int qd = 0; qd < 4; ++qd) {
        float2 aLA = zero2, aHA = zero2, aLB = zero2, aHB = zero2;
#pragma unroll
        for (int q = 0; q < 4; ++q) {
            float2 wL = *(const float2*)(wwp + (2*qd)*8 + 2*q);
            float2 wH = *(const float2*)(wwp + (2*qd+1)*8 + 2*q);
            aLA = pk_fma_vs(y2A[q], wL, aLA);
            aHA = pk_fma_vs(y2A[q], wH, aHA);
            aLB = pk_fma_vs(y2B[q], wL, aLB);
            aHB = pk_fma_vs(y2B[q], wH, aHB);
        }
        ywA[qd] = make_float2(aLA.x + aLA.y, aHA.x + aHA.y);
        ywB[qd] = make_float2(aLB.x + aLB.y, aHB.x + aHB.y);
    }
    WSYNC();   // y2 rows visible
    float kyA[10], kyB[10];
#pragma unroll
    for (int m = 0; m < 10; ++m) {
        const float4 p = *(const float4*)(slab + m * 12);
        const float4 r = *(const float4*)(slab + m * 12 + 4);
        const float2 pa = make_float2(p.x, p.y), pb = make_float2(p.z, p.w);
        const float2 ra = make_float2(r.x, r.y), rb = make_float2(r.z, r.w);
        float2 aA = pk_mul2(ywA[0], pa);
        aA = pk_fma2(ywA[1], pb, aA);
        aA = pk_fma2(ywA[2], ra, aA);
        aA = pk_fma2(ywA[3], rb, aA);
        kyA[m] = (aA.x + aA.y) * LOG2E;
        float2 aB = pk_mul2(ywB[0], pa);
        aB = pk_fma2(ywB[1], pb, aB);
        aB = pk_fma2(ywB[2], ra, aB);
        aB = pk_fma2(ywB[3], rb, aB);
        kyB[m] = (aB.x + aB.y) * LOG2E;
    }
    WSYNC();   // all y2 reads done; region reusable for ky rows (stride 10)
    {
        float* kb = slab + n0 * 10;
        *(float4*)(kb +  0) = make_float4(kyA[0], kyA[1], kyA[2], kyA[3]);
        *(float4*)(kb +  4) = make_float4(kyA[4], kyA[5], kyA[6], kyA[7]);
        *(float4*)(kb +  8) = make_float4(kyA[8], kyA[9], kyB[0], kyB[1]);
        *(float4*)(kb + 12) = make_float4(kyB[2], kyB[3], kyB[4], kyB[5]);
        *(float4*)(kb + 16) = make_float4(kyB[6], kyB[7], kyB[8], kyB[9]);
    }
    *(float2*)(slab + 120 + n0) = tks;

    __syncthreads();   // the ONE cross-wave barrier

    // ---- t softmax over K (exp2 domain, exp-reuse) ----
    {
        const float2 v0 = *(const float2*)(sm + (0*GPW + gg)*SLAB + 120 + n0);
        const float2 v1 = *(const float2*)(sm + (1*GPW + gg)*SLAB + 120 + n0);
        const float2 v2 = *(const float2*)(sm + (2*GPW + gg)*SLAB + 120 + n0);
        const float2 v3 = *(const float2*)(sm + (3*GPW + gg)*SLAB + 120 + n0);
        const float mxA = fmaxf(fmaxf(v0.x, v1.x), fmaxf(v2.x, v3.x));
        const float mxB = fmaxf(fmaxf(v0.y, v1.y), fmaxf(v2.y, v3.y));
        const float e0A = fexp2(v0.x-mxA), e1A = fexp2(v1.x-mxA);
        const float e2A = fexp2(v2.x-mxA), e3A = fexp2(v3.x-mxA);
        const float e0B = fexp2(v0.y-mxB), e1B = fexp2(v1.y-mxB);
        const float e2B = fexp2(v2.y-mxB), e3B = fexp2(v3.y-mxB);
        const float dA = e0A + e1A + e2A + e3A;
        const float dB = e0B + e1B + e2B + e3B;
        const float oA = (w == 0) ? e0A : (w == 1) ? e1A : (w == 2) ? e2A : e3A;
        const float oB = (w == 0) ? e0B : (w == 1) ? e1B : (w == 2) ? e2B : e3B;
        if (valid)
            *(float2*)(out + OFF_TJ + (size_t)g * 10 + n0) =
                make_float2(oA * rcpf(dA), oB * rcpf(dB));
    }
    // ---- k_ij softmax over K (exp2 domain, exp-reuse), q-chunked ----
    {
        const float* s0 = sm + (0*GPW + gg)*SLAB + n0 * 10;
        const float* s1 = sm + (1*GPW + gg)*SLAB + n0 * 10;
        const float* s2 = sm + (2*GPW + gg)*SLAB + n0 * 10;
        const float* s3 = sm + (3*GPW + gg)*SLAB + n0 * 10;
        float* po = out + (size_t)g * 100 + n0 * 10;
#pragma unroll
        for (int q = 0; q < 5; ++q) {
            const float4 a = *(const float4*)(s0 + 4*q);
            const float4 b = *(const float4*)(s1 + 4*q);
            const float4 c = *(const float4*)(s2 + 4*q);
            const float4 d = *(const float4*)(s3 + 4*q);
            float o[4];
#pragma unroll
            for (int e = 0; e < 4; ++e) {
                const float va = (&a.x)[e], vb = (&b.x)[e], vc = (&c.x)[e], vd = (&d.x)[e];
                const float mx = fmaxf(fmaxf(va, vb), fmaxf(vc, vd));
                const float ea = fexp2(va-mx), eb = fexp2(vb-mx);
                const float ec = fexp2(vc-mx), ed = fexp2(vd-mx);
                const float den = ea + eb + ec + ed;
                const float own = (w == 0) ? ea : (w == 1) ? eb : (w == 2) ? ec : ed;
                o[e] = own * rcpf(den);
            }
            if (valid) *(float4*)(po + 4*q) = make_float4(o[0], o[1], o[2], o[3]);
        }
    }
}

extern "C" void kernel_launch(void* const* d_in, const int* in_sizes, int n_in,
                              void* d_out, int out_size, void* d_ws, size_t ws_size,
                              hipStream_t stream) {
    const float* x   = (const float*)d_in[0];
    // d_in[1] = edge_index: deterministic pattern, never read
    const float* ew  = (const float*)d_in[2];
    const float* eig = (const float*)d_in[6];
    const float* a0  = (const float*)d_in[7];
    const float* W0  = (const float*)d_in[8];
    const float* b0  = (const float*)d_in[9];
    const float* W1  = (const float*)d_in[10];
    const float* b1  = (const float*)d_in[11];
    const float* bpw = (const float*)d_in[12];
    const float* cpw = (const float*)d_in[13];
    const float* www = (const float*)d_in[14];
    float* out = (float*)d_out;

    const int grid = (BATCH + GPW - 1) / GPW;   // 2731
    gnn_fused<<<dim3(grid), dim3(NTHREADS), 0, stream>>>(
        x, ew, eig, a0, W0, b0, W1, b1, bpw, cpw, www, out);
}

// Round 9
// 135.059 us; speedup vs baseline: 1.0997x; 1.0997x over previous
//
#include <hip/hip_runtime.h>

#define KK 4
#define BATCH 32768
#define NN 10
#define GPW 12           // graphs per wave: 12 b's; 5 lanes/graph, 2 nodes/lane
#define SLAB 132         // dwords per graph slab; 132 % 32 = 4 -> 2-way max on slab spread
#define NTHREADS 256     // 4 waves; wave w == k index

static constexpr size_t OFF_AIK = (size_t)KK * BATCH * NN * NN;           // 13107200
static constexpr size_t OFF_TJ  = OFF_AIK + (size_t)KK * BATCH * NN;      // 14417920
static constexpr size_t OFF_R   = OFF_TJ  + (size_t)KK * BATCH * NN;      // 15728640
static constexpr size_t OFF_RT  = OFF_R   + (size_t)KK * BATCH * NN * NN; // 28835840

// slab layout (dwords):
//   [0..100)   wt transpose (early); h/y2 exchange rows at n*12 [0..120);
//              ky rows at n*10 [0..100) (head phase)
//   [120..130) dinv (early) then t_k logits (head phase)
#define WSYNC() do { asm volatile("" ::: "memory"); \
                     __builtin_amdgcn_wave_barrier(); \
                     asm volatile("" ::: "memory"); } while (0)

__device__ __forceinline__ float rcpf(float x) {
#if __has_builtin(__builtin_amdgcn_rcpf)
    return __builtin_amdgcn_rcpf(x);
#else
    return 1.f / x;
#endif
}
__device__ __forceinline__ float fexp2(float x) {
#if __has_builtin(__builtin_amdgcn_exp2f)
    return __builtin_amdgcn_exp2f(x);
#else
    return exp2f(x);
#endif
}

// ---- packed fp32 helpers (VOP3P; add/mul/fma only on gfx950). Bit-exact IEEE fp32. ----
static __device__ __forceinline__ float2 pk_mul2(float2 a, float2 b) {
    float2 d; asm("v_pk_mul_f32 %0, %1, %2" : "=v"(d) : "v"(a), "v"(b)); return d; }
static __device__ __forceinline__ float2 pk_fma2(float2 a, float2 b, float2 c) {
    float2 d; asm("v_pk_fma_f32 %0, %1, %2, %3" : "=v"(d) : "v"(a), "v"(b), "v"(c)); return d; }
static __device__ __forceinline__ float2 pk_fma_blo(float2 a, float2 b, float2 c) {
    float2 d; asm("v_pk_fma_f32 %0, %1, %2, %3 op_sel_hi:[0,1,1]"
                  : "=v"(d) : "v"(a), "v"(b), "v"(c)); return d; }
static __device__ __forceinline__ float2 pk_fma_bhi(float2 a, float2 b, float2 c) {
    float2 d; asm("v_pk_fma_f32 %0, %1, %2, %3 op_sel:[1,0,0] op_sel_hi:[1,1,1]"
                  : "=v"(d) : "v"(a), "v"(b), "v"(c)); return d; }
static __device__ __forceinline__ float2 pk_fma_blo_s(float2 a, float2 bs, float2 c) {
    float2 d; asm("v_pk_fma_f32 %0, %1, %2, %3 op_sel_hi:[0,1,1]"
                  : "=v"(d) : "v"(a), "s"(bs), "v"(c)); return d; }
static __device__ __forceinline__ float2 pk_fma_bhi_s(float2 a, float2 bs, float2 c) {
    float2 d; asm("v_pk_fma_f32 %0, %1, %2, %3 op_sel:[1,0,0] op_sel_hi:[1,1,1]"
                  : "=v"(d) : "v"(a), "s"(bs), "v"(c)); return d; }
static __device__ __forceinline__ float2 pk_mul_blo_s(float2 a, float2 bs) {
    float2 d; asm("v_pk_mul_f32 %0, %1, %2 op_sel_hi:[0,1]"
                  : "=v"(d) : "v"(a), "s"(bs)); return d; }
static __device__ __forceinline__ float2 pk_fma_vs(float2 a, float2 bs, float2 c) {
    float2 d; asm("v_pk_fma_f32 %0, %1, %2, %3" : "=v"(d) : "v"(a), "s"(bs), "v"(c)); return d; }
static __device__ __forceinline__ float2 pk_add_vs(float2 a, float2 bs) {
    float2 d; asm("v_pk_add_f32 %0, %1, %2" : "=v"(d) : "v"(a), "s"(bs)); return d; }
static __device__ __forceinline__ float2 leaky2(float2 v) {
    return make_float2(fmaxf(v.x, 0.f) + 0.01f * fminf(v.x, 0.f),
                       fmaxf(v.y, 0.f) + 0.01f * fminf(v.y, 0.f)); }

__global__ __launch_bounds__(NTHREADS, 2)
void gnn_fused(const float* __restrict__ xin,
               const float* __restrict__ ew,
               const float* __restrict__ eigen,
               const float* __restrict__ a0p,
               const float* __restrict__ W0p,
               const float* __restrict__ b0p,
               const float* __restrict__ W1p,
               const float* __restrict__ b1p,
               const float* __restrict__ bpp,
               const float* __restrict__ cpp,
               const float* __restrict__ wwp,
               float* __restrict__ out)
{
    __shared__ __align__(16) float sm[KK * GPW * SLAB];   // 25,344 B

    const float LOG2E = 1.4426950408889634f;
    const float2 zero2 = make_float2(0.f, 0.f);

    const int t = threadIdx.x;
    const int l = t & 63;
    const int w = t >> 6;             // k index
    int gg = l / 5;                   // graph slot 0..12
    const int t5 = l - gg * 5;        // 0..4 (lanes 60..63 -> t5 0..3)
    if (gg > 11) gg = 11;             // dup lanes mirror graph 11 (identical writes)
    const int n0 = 2 * t5, n1 = n0 + 1;
    const int bb = blockIdx.x * GPW + gg;
    const bool valid = (l < 60) && (bb < BATCH);
    const int bbc = (bb < BATCH) ? bb : (BATCH - 1);
    const int g   = w * BATCH + bbc;

    float* slab = sm + (w * GPW + gg) * SLAB;

    const float* xb = xin + ((size_t)g * 10 + n0) * 3;   // 6 floats, 8B-aligned
    const float2 f0 = *(const float2*)(xb);
    const float2 f1 = *(const float2*)(xb + 2);
    const float2 f2 = *(const float2*)(xb + 4);
    // node A: (f0.x, f0.y, f1.x)   node B: (f1.y, f2.x, f2.y)
    const float eig = eigen[g];
    const float a0v = a0p[0];
    const float2 eig2 = make_float2(eig, eig);

    // ---- own two outgoing edge-weight rows DIRECT from global; build wout; store R ----
    {
        float rw[18];
        const float* rp = ew + (size_t)g * 90 + n0 * 9;
#pragma unroll
        for (int i = 0; i < 9; ++i) {
            float2 v = *(const float2*)(rp + 2 * i);
            rw[2*i] = v.x; rw[2*i+1] = v.y;
        }
        float wA[10], wB[10];
#pragma unroll
        for (int j = 0; j < 10; ++j) {
            wA[j] = (j == n0) ? 0.f : ((j < n0) ? rw[j]   : rw[j-1]);
            wB[j] = (j == n1) ? 0.f : ((j < n1) ? rw[9+j] : rw[8+j]);
        }
        if (valid) {
            float* pr = out + OFF_R + (size_t)g * 100 + n0 * 10;
            float2 m0 = pk_mul2(make_float2(wA[0], wA[1]), eig2);
            float2 m1 = pk_mul2(make_float2(wA[2], wA[3]), eig2);
            float2 m2 = pk_mul2(make_float2(wA[4], wA[5]), eig2);
            float2 m3 = pk_mul2(make_float2(wA[6], wA[7]), eig2);
            float2 m4 = pk_mul2(make_float2(wA[8], wA[9]), eig2);
            float2 m5 = pk_mul2(make_float2(wB[0], wB[1]), eig2);
            float2 m6 = pk_mul2(make_float2(wB[2], wB[3]), eig2);
            float2 m7 = pk_mul2(make_float2(wB[4], wB[5]), eig2);
            float2 m8 = pk_mul2(make_float2(wB[6], wB[7]), eig2);
            float2 m9 = pk_mul2(make_float2(wB[8], wB[9]), eig2);
            *(float4*)(pr +  0) = make_float4(m0.x, m0.y, m1.x, m1.y);
            *(float4*)(pr +  4) = make_float4(m2.x, m2.y, m3.x, m3.y);
            *(float4*)(pr +  8) = make_float4(m4.x, m4.y, m5.x, m5.y);
            *(float4*)(pr + 12) = make_float4(m6.x, m6.y, m7.x, m7.y);
            *(float4*)(pr + 16) = make_float4(m8.x, m8.y, m9.x, m9.y);
        }
        // transpose through LDS: wt[j][n] = w(n->j)
#pragma unroll
        for (int j = 0; j < 10; ++j)
            *(float2*)(slab + j * 10 + n0) = make_float2(wA[j], wB[j]);
    }
    WSYNC();
    float inA[10], inB[10];
    {
        const float* rp = slab + n0 * 10;     // 20 contiguous floats, 16B-aligned
        float4 v0 = *(const float4*)(rp +  0);
        float4 v1 = *(const float4*)(rp +  4);
        float4 v2 = *(const float4*)(rp +  8);
        float4 v3 = *(const float4*)(rp + 12);
        float4 v4 = *(const float4*)(rp + 16);
        inA[0]=v0.x; inA[1]=v0.y; inA[2]=v0.z; inA[3]=v0.w;
        inA[4]=v1.x; inA[5]=v1.y; inA[6]=v1.z; inA[7]=v1.w;
        inA[8]=v2.x; inA[9]=v2.y; inB[0]=v2.z; inB[1]=v2.w;
        inB[2]=v3.x; inB[3]=v3.y; inB[4]=v3.z; inB[5]=v3.w;
        inB[6]=v4.x; inB[7]=v4.y; inB[8]=v4.z; inB[9]=v4.w;
    }
    float degA = 0.f, degB = 0.f;
#pragma unroll
    for (int m = 0; m < 10; ++m) { degA += inA[m]; degB += inB[m]; }

    // ---- R_t rows ----
    if (valid) {
        float* pt = out + OFF_RT + (size_t)g * 100 + n0 * 10;
        float2 m0 = pk_mul2(make_float2(inA[0], inA[1]), eig2);
        float2 m1 = pk_mul2(make_float2(inA[2], inA[3]), eig2);
        float2 m2 = pk_mul2(make_float2(inA[4], inA[5]), eig2);
        float2 m3 = pk_mul2(make_float2(inA[6], inA[7]), eig2);
        float2 m4 = pk_mul2(make_float2(inA[8], inA[9]), eig2);
        float2 m5 = pk_mul2(make_float2(inB[0], inB[1]), eig2);
        float2 m6 = pk_mul2(make_float2(inB[2], inB[3]), eig2);
        float2 m7 = pk_mul2(make_float2(inB[4], inB[5]), eig2);
        float2 m8 = pk_mul2(make_float2(inB[6], inB[7]), eig2);
        float2 m9 = pk_mul2(make_float2(inB[8], inB[9]), eig2);
        *(float4*)(pt +  0) = make_float4(m0.x, m0.y, m1.x, m1.y);
        *(float4*)(pt +  4) = make_float4(m2.x, m2.y, m3.x, m3.y);
        *(float4*)(pt +  8) = make_float4(m4.x, m4.y, m5.x, m5.y);
        *(float4*)(pt + 12) = make_float4(m6.x, m6.y, m7.x, m7.y);
        *(float4*)(pt + 16) = make_float4(m8.x, m8.y, m9.x, m9.y);
    }

    // ---- dinv exchange ----
    const float dvA = (degA > 0.f) ? __frsqrt_rn(degA) : 0.f;
    const float dvB = (degB > 0.f) ? __frsqrt_rn(degB) : 0.f;
    *(float2*)(slab + 120 + n0) = make_float2(dvA, dvB);
    WSYNC();
    float2 arA[5], arB[5];
    {
        float dinv[10];
        float4 da = *(const float4*)(slab + 120);
        float4 db = *(const float4*)(slab + 124);
        float2 dc = *(const float2*)(slab + 128);
        dinv[0]=da.x; dinv[1]=da.y; dinv[2]=da.z; dinv[3]=da.w;
        dinv[4]=db.x; dinv[5]=db.y; dinv[6]=db.z; dinv[7]=db.w;
        dinv[8]=dc.x; dinv[9]=dc.y;
        const float2 dvA2 = make_float2(dvA, dvA);
        const float2 dvB2 = make_float2(dvB, dvB);
#pragma unroll
        for (int q = 0; q < 5; ++q) {
            const float2 dq = make_float2(dinv[2*q], dinv[2*q+1]);
            arA[q] = pk_mul2(pk_mul2(dq, make_float2(inA[2*q], inA[2*q+1])), dvA2);
            arB[q] = pk_mul2(pk_mul2(dq, make_float2(inB[2*q], inB[2*q+1])), dvB2);
        }
    }

    // ================= TAGConv layer 0: 3 -> 16, feature-packed, 2 nodes =================
    float2 habA = make_float2(f0.x, f0.y), hcjA = make_float2(f1.x, 0.f);
    float2 habB = make_float2(f1.y, f2.x), hcjB = make_float2(f2.y, 0.f);
    const float x2A = f1.x, x2B = f2.y;
    float2 accA0[8], accB0[8];
#pragma unroll
    for (int q = 0; q < 8; ++q) {
        float2 wa = *(const float2*)(W0p + 2*q);
        float2 wb = *(const float2*)(W0p + 16 + 2*q);
        float2 wc = *(const float2*)(W0p + 32 + 2*q);
        accA0[q] = pk_mul_blo_s(habA, wa);
        accA0[q] = pk_fma_bhi_s(habA, wb, accA0[q]);
        accA0[q] = pk_fma_blo_s(hcjA, wc, accA0[q]);
        accB0[q] = pk_mul_blo_s(habB, wa);
        accB0[q] = pk_fma_bhi_s(habB, wb, accB0[q]);
        accB0[q] = pk_fma_blo_s(hcjB, wc, accB0[q]);
    }
#pragma unroll
    for (int hop = 1; hop <= 3; ++hop) {
        *(float4*)(slab + n0 * 12) = make_float4(habA.x, habA.y, hcjA.x, hcjA.y);
        *(float4*)(slab + n1 * 12) = make_float4(habB.x, habB.y, hcjB.x, hcjB.y);
        WSYNC();
        float2 nabA = zero2, ncjA = zero2, nabB = zero2, ncjB = zero2;
#pragma unroll
        for (int m = 0; m < 10; ++m) {
            const float4 hm = *(const float4*)(slab + m * 12);
            const float2 hx = make_float2(hm.x, hm.y);
            const float2 hz = make_float2(hm.z, hm.w);
            const float2 aAm = arA[m >> 1], aBm = arB[m >> 1];
            if ((m & 1) == 0) {
                nabA = pk_fma_blo(aAm, hx, nabA); ncjA = pk_fma_blo(aAm, hz, ncjA);
                nabB = pk_fma_blo(aBm, hx, nabB); ncjB = pk_fma_blo(aBm, hz, ncjB);
            } else {
                nabA = pk_fma_bhi(aAm, hx, nabA); ncjA = pk_fma_bhi(aAm, hz, ncjA);
                nabB = pk_fma_bhi(aBm, hx, nabB); ncjB = pk_fma_bhi(aBm, hz, ncjB);
            }
        }
        WSYNC();
#pragma unroll
        for (int q = 0; q < 8; ++q) {
            float2 wa = *(const float2*)(W0p + hop*48 + 2*q);
            float2 wb = *(const float2*)(W0p + hop*48 + 16 + 2*q);
            float2 wc = *(const float2*)(W0p + hop*48 + 32 + 2*q);
            accA0[q] = pk_fma_blo_s(nabA, wa, accA0[q]);
            accA0[q] = pk_fma_bhi_s(nabA, wb, accA0[q]);
            accA0[q] = pk_fma_blo_s(ncjA, wc, accA0[q]);
            accB0[q] = pk_fma_blo_s(nabB, wa, accB0[q]);
            accB0[q] = pk_fma_bhi_s(nabB, wb, accB0[q]);
            accB0[q] = pk_fma_blo_s(ncjB, wc, accB0[q]);
        }
        habA = nabA; hcjA = ncjA; habB = nabB; hcjB = ncjB;
    }
    float2 y1A[8], y1B[8];
#pragma unroll
    for (int q = 0; q < 8; ++q) {
        float2 b2 = *(const float2*)(b0p + 2*q);
        y1A[q] = leaky2(pk_add_vs(accA0[q], b2));
        y1B[q] = leaky2(pk_add_vs(accB0[q], b2));
    }

    // ===== TAGConv layer 1: 16 -> 8, Horner, feature-packed, 2 nodes =====
    float2 curA[4], curB[4];
#pragma unroll
    for (int q = 0; q < 4; ++q) {
        float2 w0 = *(const float2*)(W1p + 384 + 2*q);
        curA[q] = pk_mul_blo_s(y1A[0], w0);
        curB[q] = pk_mul_blo_s(y1B[0], w0);
        float2 w1 = *(const float2*)(W1p + 384 + 8 + 2*q);
        curA[q] = pk_fma_bhi_s(y1A[0], w1, curA[q]);
        curB[q] = pk_fma_bhi_s(y1B[0], w1, curB[q]);
#pragma unroll
        for (int p8 = 1; p8 < 8; ++p8) {
            float2 wl = *(const float2*)(W1p + 384 + (2*p8)*8 + 2*q);
            float2 wh = *(const float2*)(W1p + 384 + (2*p8+1)*8 + 2*q);
            curA[q] = pk_fma_blo_s(y1A[p8], wl, curA[q]);
            curA[q] = pk_fma_bhi_s(y1A[p8], wh, curA[q]);
            curB[q] = pk_fma_blo_s(y1B[p8], wl, curB[q]);
            curB[q] = pk_fma_bhi_s(y1B[p8], wh, curB[q]);
        }
    }
#pragma unroll
    for (int kh = 2; kh >= 0; --kh) {
        *(float4*)(slab + n0 * 12)     = make_float4(curA[0].x, curA[0].y, curA[1].x, curA[1].y);
        *(float4*)(slab + n0 * 12 + 4) = make_float4(curA[2].x, curA[2].y, curA[3].x, curA[3].y);
        *(float4*)(slab + n1 * 12)     = make_float4(curB[0].x, curB[0].y, curB[1].x, curB[1].y);
        *(float4*)(slab + n1 * 12 + 4) = make_float4(curB[2].x, curB[2].y, curB[3].x, curB[3].y);
        WSYNC();
        float2 agA[4] = {zero2, zero2, zero2, zero2};
        float2 agB[4] = {zero2, zero2, zero2, zero2};
#pragma unroll
        for (int m = 0; m < 10; ++m) {
            const float4 p = *(const float4*)(slab + m * 12);
            const float4 r = *(const float4*)(slab + m * 12 + 4);
            const float2 pa = make_float2(p.x, p.y), pb = make_float2(p.z, p.w);
            const float2 ra = make_float2(r.x, r.y), rb = make_float2(r.z, r.w);
            const float2 aAm = arA[m >> 1], aBm = arB[m >> 1];
            if ((m & 1) == 0) {
                agA[0] = pk_fma_blo(aAm, pa, agA[0]); agA[1] = pk_fma_blo(aAm, pb, agA[1]);
                agA[2] = pk_fma_blo(aAm, ra, agA[2]); agA[3] = pk_fma_blo(aAm, rb, agA[3]);
                agB[0] = pk_fma_blo(aBm, pa, agB[0]); agB[1] = pk_fma_blo(aBm, pb, agB[1]);
                agB[2] = pk_fma_blo(aBm, ra, agB[2]); agB[3] = pk_fma_blo(aBm, rb, agB[3]);
            } else {
                agA[0] = pk_fma_bhi(aAm, pa, agA[0]); agA[1] = pk_fma_bhi(aAm, pb, agA[1]);
                agA[2] = pk_fma_bhi(aAm, ra, agA[2]); agA[3] = pk_fma_bhi(aAm, rb, agA[3]);
                agB[0] = pk_fma_bhi(aBm, pa, agB[0]); agB[1] = pk_fma_bhi(aBm, pb, agB[1]);
                agB[2] = pk_fma_bhi(aBm, ra, agB[2]); agB[3] = pk_fma_bhi(aBm, rb, agB[3]);
            }
        }
        WSYNC();
#pragma unroll
        for (int q = 0; q < 4; ++q) {
            curA[q] = agA[q]; curB[q] = agB[q];
#pragma unroll
            for (int p8 = 0; p8 < 8; ++p8) {
                float2 wl = *(const float2*)(W1p + kh*128 + (2*p8)*8 + 2*q);
                float2 wh = *(const float2*)(W1p + kh*128 + (2*p8+1)*8 + 2*q);
                curA[q] = pk_fma_blo_s(y1A[p8], wl, curA[q]);
                curA[q] = pk_fma_bhi_s(y1A[p8], wh, curA[q]);
                curB[q] = pk_fma_blo_s(y1B[p8], wl, curB[q]);
                curB[q] = pk_fma_bhi_s(y1B[p8], wh, curB[q]);
            }
        }
    }
    float2 y2A[4], y2B[4];
#pragma unroll
    for (int q = 0; q < 4; ++q) {
        float2 b2 = *(const float2*)(b1p + 2*q);
        y2A[q] = leaky2(pk_add_vs(curA[q], b2));
        y2B[q] = leaky2(pk_add_vs(curB[q], b2));
    }

    // ================= heads =================
    *(float4*)(slab + n0 * 12)     = make_float4(y2A[0].x, y2A[0].y, y2A[1].x, y2A[1].y);
    *(float4*)(slab + n0 * 12 + 4) = make_float4(y2A[2].x, y2A[2].y, y2A[3].x, y2A[3].y);
    *(float4*)(slab + n1 * 12)     = make_float4(y2B[0].x, y2B[0].y, y2B[1].x, y2B[1].y);
    *(float4*)(slab + n1 * 12 + 4) = make_float4(y2B[2].x, y2B[2].y, y2B[3].x, y2B[3].y);

    float2 aaA = zero2, aaB = zero2, ttA = zero2, ttB = zero2;
#pragma unroll
    for (int q = 0; q < 4; ++q) {
        float2 bp2 = *(const float2*)(bpp + 2*q);
        float2 cp2 = *(const float2*)(cpp + 2*q);
        aaA = pk_fma_vs(y2A[q], bp2, aaA);
        aaB = pk_fma_vs(y2B[q], bp2, aaB);
        ttA = pk_fma_vs(y2A[q], cp2, ttA);
        ttB = pk_fma_vs(y2B[q], cp2, ttB);
    }
    if (valid)
        *(float2*)(out + OFF_AIK + (size_t)g * 10 + n0) =
            make_float2(a0v + fmaxf(aaA.x + aaA.y, 0.f), a0v + fmaxf(aaB.x + aaB.y, 0.f));

    float tkA = (ttA.x + ttA.y) * (1.f - fmaxf(x2A, 0.f));
    float tkB = (ttB.x + ttB.y) * (1.f - fmaxf(x2B, 0.f));
    if (tkA == 0.f) tkA = -1e10f;
    if (tkB == 0.f) tkB = -1e10f;
    const float2 tks = make_float2(tkA * LOG2E, tkB * LOG2E);

    float2 ywA[4], ywB[4];   // (yw[2qd], yw[2qd+1]) per node
#pragma unroll
    for (int qd = 0; qd < 4; ++qd) {
        float2 aLA = zero2, aHA = zero2, aLB = zero2, aHB = zero2;
#pragma unroll
        for (int q = 0; q < 4; ++q) {
            float2 wL = *(const float2*)(wwp + (2*qd)*8 + 2*q);
            float2 wH = *(const float2*)(wwp + (2*qd+1)*8 + 2*q);
            aLA = pk_fma_vs(y2A[q], wL, aLA);
            aHA = pk_fma_vs(y2A[q], wH, aHA);
            aLB = pk_fma_vs(y2B[q], wL, aLB);
            aHB = pk_fma_vs(y2B[q], wH, aHB);
        }
        ywA[qd] = make_float2(aLA.x + aLA.y, aHA.x + aHA.y);
        ywB[qd] = make_float2(aLB.x + aLB.y, aHB.x + aHB.y);
    }
    WSYNC();   // y2 rows visible
    float kyA[10], kyB[10];
#pragma unroll
    for (int m = 0; m < 10; ++m) {
        const float4 p = *(const float4*)(slab + m * 12);
        const float4 r = *(const float4*)(slab + m * 12 + 4);
        const float2 pa = make_float2(p.x, p.y), pb = make_float2(p.z, p.w);
        const float2 ra = make_float2(r.x, r.y), rb = make_float2(r.z, r.w);
        float2 aA = pk_mul2(ywA[0], pa);
        aA = pk_fma2(ywA[1], pb, aA);
        aA = pk_fma2(ywA[2], ra, aA);
        aA = pk_fma2(ywA[3], rb, aA);
        kyA[m] = (aA.x + aA.y) * LOG2E;
        float2 aB = pk_mul2(ywB[0], pa);
        aB = pk_fma2(ywB[1], pb, aB);
        aB = pk_fma2(ywB[2], ra, aB);
        aB = pk_fma2(ywB[3], rb, aB);
        kyB[m] = (aB.x + aB.y) * LOG2E;
    }
    WSYNC();   // all y2 reads done; region reusable for ky rows (stride 10)
    {
        float* kb = slab + n0 * 10;
        *(float4*)(kb +  0) = make_float4(kyA[0], kyA[1], kyA[2], kyA[3]);
        *(float4*)(kb +  4) = make_float4(kyA[4], kyA[5], kyA[6], kyA[7]);
        *(float4*)(kb +  8) = make_float4(kyA[8], kyA[9], kyB[0], kyB[1]);
        *(float4*)(kb + 12) = make_float4(kyB[2], kyB[3], kyB[4], kyB[5]);
        *(float4*)(kb + 16) = make_float4(kyB[6], kyB[7], kyB[8], kyB[9]);
    }
    *(float2*)(slab + 120 + n0) = tks;

    __syncthreads();   // the ONE cross-wave barrier

    // ---- t softmax over K (exp2 domain, exp-reuse) ----
    {
        const float2 v0 = *(const float2*)(sm + (0*GPW + gg)*SLAB + 120 + n0);
        const float2 v1 = *(const float2*)(sm + (1*GPW + gg)*SLAB + 120 + n0);
        const float2 v2 = *(const float2*)(sm + (2*GPW + gg)*SLAB + 120 + n0);
        const float2 v3 = *(const float2*)(sm + (3*GPW + gg)*SLAB + 120 + n0);
        const float mxA = fmaxf(fmaxf(v0.x, v1.x), fmaxf(v2.x, v3.x));
        const float mxB = fmaxf(fmaxf(v0.y, v1.y), fmaxf(v2.y, v3.y));
        const float e0A = fexp2(v0.x-mxA), e1A = fexp2(v1.x-mxA);
        const float e2A = fexp2(v2.x-mxA), e3A = fexp2(v3.x-mxA);
        const float e0B = fexp2(v0.y-mxB), e1B = fexp2(v1.y-mxB);
        const float e2B = fexp2(v2.y-mxB), e3B = fexp2(v3.y-mxB);
        const float dA = e0A + e1A + e2A + e3A;
        const float dB = e0B + e1B + e2B + e3B;
        const float oA = (w == 0) ? e0A : (w == 1) ? e1A : (w == 2) ? e2A : e3A;
        const float oB = (w == 0) ? e0B : (w == 1) ? e1B : (w == 2) ? e2B : e3B;
        if (valid)
            *(float2*)(out + OFF_TJ + (size_t)g * 10 + n0) =
                make_float2(oA * rcpf(dA), oB * rcpf(dB));
    }
    // ---- k_ij softmax over K (exp2 domain, exp-reuse), q-chunked ----
    {
        const float* s0 = sm + (0*GPW + gg)*SLAB + n0 * 10;
        const float* s1 = sm + (1*GPW + gg)*SLAB + n0 * 10;
        const float* s2 = sm + (2*GPW + gg)*SLAB + n0 * 10;
        const float* s3 = sm + (3*GPW + gg)*SLAB + n0 * 10;
        float* po = out + (size_t)g * 100 + n0 * 10;
#pragma unroll
        for (int q = 0; q < 5; ++q) {
            const float4 a = *(const float4*)(s0 + 4*q);
            const float4 b = *(const float4*)(s1 + 4*q);
            const float4 c = *(const float4*)(s2 + 4*q);
            const float4 d = *(const float4*)(s3 + 4*q);
            float o[4];
#pragma unroll
            for (int e = 0; e < 4; ++e) {
                const float va = (&a.x)[e], vb = (&b.x)[e], vc = (&c.x)[e], vd = (&d.x)[e];
                const float mx = fmaxf(fmaxf(va, vb), fmaxf(vc, vd));
                const float ea = fexp2(va-mx), eb = fexp2(vb-mx);
                const float ec = fexp2(vc-mx), ed = fexp2(vd-mx);
                const float den = ea + eb + ec + ed;
                const float own = (w == 0) ? ea : (w == 1) ? eb : (w == 2) ? ec : ed;
                o[e] = own * rcpf(den);
            }
            if (valid) *(float4*)(po + 4*q) = make_float4(o[0], o[1], o[2], o[3]);
        }
    }
}

extern "C" void kernel_launch(void* const* d_in, const int* in_sizes, int n_in,
                              void* d_out, int out_size, void* d_ws, size_t ws_size,
                              hipStream_t stream) {
    const float* x   = (const float*)d_in[0];
    // d_in[1] = edge_index: deterministic pattern, never read
    const float* ew  = (const float*)d_in[2];
    const float* eig = (const float*)d_in[6];
    const float* a0  = (const float*)d_in[7];
    const float* W0  = (const float*)d_in[8];
    const float* b0  = (const float*)d_in[9];
    const float* W1  = (const float*)d_in[10];
    const float* b1  = (const float*)d_in[11];
    const float* bpw = (const float*)d_in[12];
    const float* cpw = (const float*)d_in[13];
    const float* www = (const float*)d_in[14];
    float* out = (float*)d_out;

    const int grid = (BATCH + GPW - 1) / GPW;   // 2731
    gnn_fused<<<dim3(grid), dim3(NTHREADS), 0, stream>>>(
        x, ew, eig, a0, W0, b0, W1, b1, bpw, cpw, www, out);
}

// Round 10
// 76.116 us; speedup vs baseline: 1.9513x; 1.7744x over previous
//
#include <hip/hip_runtime.h>

#define KK 4
#define BATCH 32768
#define NN 10
#define GPW 6            // graphs per wave (10 lanes each, 60 of 64 lanes)
#define SLAB 132         // dwords per graph slab; 132 % 32 = 4 -> conflict-free mac broadcasts
#define NTHREADS 256     // 4 waves; wave w == k index

static constexpr size_t OFF_AIK = (size_t)KK * BATCH * NN * NN;           // 13107200
static constexpr size_t OFF_TJ  = OFF_AIK + (size_t)KK * BATCH * NN;      // 14417920
static constexpr size_t OFF_R   = OFF_TJ  + (size_t)KK * BATCH * NN;      // 15728640
static constexpr size_t OFF_RT  = OFF_R   + (size_t)KK * BATCH * NN * NN; // 28835840

#define WSYNC() do { asm volatile("" ::: "memory"); \
                     __builtin_amdgcn_wave_barrier(); \
                     asm volatile("" ::: "memory"); } while (0)

__device__ __forceinline__ float rcpf(float x) {
#if __has_builtin(__builtin_amdgcn_rcpf)
    return __builtin_amdgcn_rcpf(x);
#else
    return 1.f / x;
#endif
}
__device__ __forceinline__ float fexp2(float x) {
#if __has_builtin(__builtin_amdgcn_exp2f)
    return __builtin_amdgcn_exp2f(x);
#else
    return exp2f(x);
#endif
}

// ---- packed fp32 helpers (VOP3P; add/mul/fma only on gfx950). Bit-exact IEEE fp32. ----
static __device__ __forceinline__ float2 pk_mul2(float2 a, float2 b) {
    float2 d; asm("v_pk_mul_f32 %0, %1, %2" : "=v"(d) : "v"(a), "v"(b)); return d; }
static __device__ __forceinline__ float2 pk_add2(float2 a, float2 b) {
    float2 d; asm("v_pk_add_f32 %0, %1, %2" : "=v"(d) : "v"(a), "v"(b)); return d; }
static __device__ __forceinline__ float2 pk_fma2(float2 a, float2 b, float2 c) {
    float2 d; asm("v_pk_fma_f32 %0, %1, %2, %3" : "=v"(d) : "v"(a), "v"(b), "v"(c)); return d; }
static __device__ __forceinline__ float2 pk_fma_blo(float2 a, float2 b, float2 c) {
    float2 d; asm("v_pk_fma_f32 %0, %1, %2, %3 op_sel_hi:[0,1,1]"
                  : "=v"(d) : "v"(a), "v"(b), "v"(c)); return d; }
static __device__ __forceinline__ float2 pk_fma_bhi(float2 a, float2 b, float2 c) {
    float2 d; asm("v_pk_fma_f32 %0, %1, %2, %3 op_sel:[1,0,0] op_sel_hi:[1,1,1]"
                  : "=v"(d) : "v"(a), "v"(b), "v"(c)); return d; }
static __device__ __forceinline__ float2 pk_fma_blo_s(float2 a, float2 bs, float2 c) {
    float2 d; asm("v_pk_fma_f32 %0, %1, %2, %3 op_sel_hi:[0,1,1]"
                  : "=v"(d) : "v"(a), "s"(bs), "v"(c)); return d; }
static __device__ __forceinline__ float2 pk_fma_bhi_s(float2 a, float2 bs, float2 c) {
    float2 d; asm("v_pk_fma_f32 %0, %1, %2, %3 op_sel:[1,0,0] op_sel_hi:[1,1,1]"
                  : "=v"(d) : "v"(a), "s"(bs), "v"(c)); return d; }
static __device__ __forceinline__ float2 pk_mul_blo_s(float2 a, float2 bs) {
    float2 d; asm("v_pk_mul_f32 %0, %1, %2 op_sel_hi:[0,1]"
                  : "=v"(d) : "v"(a), "s"(bs)); return d; }
static __device__ __forceinline__ float2 pk_fma_vs(float2 a, float2 bs, float2 c) {
    float2 d; asm("v_pk_fma_f32 %0, %1, %2, %3" : "=v"(d) : "v"(a), "s"(bs), "v"(c)); return d; }
static __device__ __forceinline__ float2 pk_add_vs(float2 a, float2 bs) {
    float2 d; asm("v_pk_add_f32 %0, %1, %2" : "=v"(d) : "v"(a), "s"(bs)); return d; }
static __device__ __forceinline__ float2 el_max2(float2 a, float2 b) {
    return make_float2(fmaxf(a.x, b.x), fmaxf(a.y, b.y)); }
static __device__ __forceinline__ float2 leaky2(float2 v) {
    return make_float2(fmaxf(v.x, 0.f) + 0.01f * fminf(v.x, 0.f),
                       fmaxf(v.y, 0.f) + 0.01f * fminf(v.y, 0.f)); }

__global__ __launch_bounds__(NTHREADS, 6)
void gnn_fused(const float* __restrict__ xin,
               const float* __restrict__ ew,
               const float* __restrict__ eigen,
               const float* __restrict__ a0p,
               const float* __restrict__ W0p,
               const float* __restrict__ b0p,
               const float* __restrict__ W1p,
               const float* __restrict__ b1p,
               const float* __restrict__ bpp,
               const float* __restrict__ cpp,
               const float* __restrict__ wwp,
               float* __restrict__ out)
{
    __shared__ __align__(16) float sm[KK * GPW * SLAB];   // 12,672 B

    const float LOG2E = 1.4426950408889634f;
    const float2 zero2 = make_float2(0.f, 0.f);

    const int t = threadIdx.x;
    const int l = t & 63;
    const int w = t >> 6;             // k index
    int s = l / 10;                   // graph in wave 0..6
    const int n = l % 10;             // node
    const bool dup = (s >= GPW);
    if (dup) s = GPW - 1;
    const int bb  = blockIdx.x * GPW + s;
    const bool valid = (!dup) && (bb < BATCH);
    const int bbc = (bb < BATCH) ? bb : (BATCH - 1);
    const int g   = w * BATCH + bbc;

    float* slab = sm + (w * GPW + s) * SLAB;

    // ---- own outgoing edge-weight row DIRECT from global ----
    float rowv[9];
    {
        const float* rp = ew + (size_t)g * 90 + n * 9;
#pragma unroll
        for (int c = 0; c < 9; ++c) rowv[c] = rp[c];
    }
    const size_t node = (size_t)g * NN + n;
    const float x0 = xin[node * 3 + 0];
    const float x1 = xin[node * 3 + 1];
    const float x2 = xin[node * 3 + 2];
    const float eig = eigen[g];
    const float a0v = a0p[0];

    float wout[10];
    wout[0] = (n == 0) ? 0.f : rowv[0];
    wout[9] = (n == 9) ? 0.f : rowv[8];
#pragma unroll
    for (int j = 1; j < 9; ++j)
        wout[j] = (j == n) ? 0.f : ((j < n) ? rowv[j] : rowv[j - 1]);

    // ---- R (row n = outgoing) ----
    if (valid) {
        float* pr = out + OFF_R + (size_t)g * 100 + n * 10;
#pragma unroll
        for (int q = 0; q < 5; ++q)
            ((float2*)pr)[q] = make_float2(wout[2*q] * eig, wout[2*q+1] * eig);
    }

    // ---- transpose through LDS: wt[j][n] = w(n->j) ----
#pragma unroll
    for (int j = 0; j < 10; ++j) slab[j * 10 + n] = wout[j];
    WSYNC();
    float2 win2[5];
    {
        const float* rp = slab + n * 10;
#pragma unroll
        for (int q = 0; q < 5; ++q) win2[q] = *(const float2*)(rp + 2 * q);
    }
    const float deg = (win2[0].x + win2[0].y) + (win2[1].x + win2[1].y)
                    + (win2[2].x + win2[2].y) + (win2[3].x + win2[3].y)
                    + (win2[4].x + win2[4].y);

    // ---- R_t (row n = incoming) ----
    if (valid) {
        float* pt = out + OFF_RT + (size_t)g * 100 + n * 10;
#pragma unroll
        for (int q = 0; q < 5; ++q)
            ((float2*)pt)[q] = make_float2(win2[q].x * eig, win2[q].y * eig);
    }

    // ---- dinv exchange ----
    const float dv = (deg > 0.f) ? __frsqrt_rn(deg) : 0.f;
    slab[120 + n] = dv;
    WSYNC();
    float2 dinv2[5];
#pragma unroll
    for (int q = 0; q < 5; ++q) dinv2[q] = *(const float2*)(slab + 120 + 2 * q);
    const float2 dv2 = make_float2(dv, dv);
    float2 arow2[5];
#pragma unroll
    for (int q = 0; q < 5; ++q)
        arow2[q] = pk_mul2(pk_mul2(dinv2[q], win2[q]), dv2);

    // ========== TAGConv layer 0: aggregation chain first (projections deferred) ==========
    const float2 x01 = make_float2(x0, x1);
    const float2 x2p = make_float2(x2, 0.f);
    float2 na_ab[3], na_cj[3];
    {
        float2 hab = x01, hcj = x2p;
#pragma unroll
        for (int hop = 0; hop < 3; ++hop) {
            *(float4*)(slab + n * 12) = make_float4(hab.x, hab.y, hcj.x, hcj.y);
            WSYNC();
            float2 nab = zero2, ncj = zero2;
#pragma unroll
            for (int m = 0; m < 10; ++m) {
                const float4 hm = *(const float4*)(slab + m * 12);
                const float2 hx = make_float2(hm.x, hm.y);
                const float2 hz = make_float2(hm.z, hm.w);
                const float2 am = arow2[m >> 1];
                if ((m & 1) == 0) {
                    nab = pk_fma_blo(am, hx, nab);
                    ncj = pk_fma_blo(am, hz, ncj);
                } else {
                    nab = pk_fma_bhi(am, hx, nab);
                    ncj = pk_fma_bhi(am, hz, ncj);
                }
            }
            WSYNC();
            na_ab[hop] = nab; na_cj[hop] = ncj;
            hab = nab; hcj = ncj;
        }
    }
    // ---- L0 projections, one dense VALU block (same accumulation order as before) ----
    float2 acc0p[8];
#pragma unroll
    for (int q = 0; q < 8; ++q) {
        float2 wa = *(const float2*)(W0p + 2*q);
        float2 wb = *(const float2*)(W0p + 16 + 2*q);
        float2 wc = *(const float2*)(W0p + 32 + 2*q);
        acc0p[q] = pk_mul_blo_s(x01, wa);
        acc0p[q] = pk_fma_bhi_s(x01, wb, acc0p[q]);
        acc0p[q] = pk_fma_blo_s(x2p, wc, acc0p[q]);
    }
#pragma unroll
    for (int hop = 1; hop <= 3; ++hop) {
        const float2 nab = na_ab[hop - 1];
        const float2 ncj = na_cj[hop - 1];
#pragma unroll
        for (int q = 0; q < 8; ++q) {
            float2 wa = *(const float2*)(W0p + hop*48 + 2*q);
            float2 wb = *(const float2*)(W0p + hop*48 + 16 + 2*q);
            float2 wc = *(const float2*)(W0p + hop*48 + 32 + 2*q);
            acc0p[q] = pk_fma_blo_s(nab, wa, acc0p[q]);
            acc0p[q] = pk_fma_bhi_s(nab, wb, acc0p[q]);
            acc0p[q] = pk_fma_blo_s(ncj, wc, acc0p[q]);
        }
    }
    float2 y1p[8];
#pragma unroll
    for (int q = 0; q < 8; ++q) {
        float2 b2 = *(const float2*)(b0p + 2*q);
        y1p[q] = leaky2(pk_add_vs(acc0p[q], b2));
    }

    // ========== TAGConv layer 1: precompute ALL projections z0..z3, then lean Horner ==========
    // z_k[q] = (y1 @ W1[k]) feature-pair q.  y1 dies after this block.
    float2 cur2[4], zk0[4], zk1[4], zk2[4];
#pragma unroll
    for (int q = 0; q < 4; ++q) {
        // z3 -> cur2 (Horner seed)
        {
            float2 w0 = *(const float2*)(W1p + 384 + 2*q);
            float2 w1 = *(const float2*)(W1p + 384 + 8 + 2*q);
            cur2[q] = pk_mul_blo_s(y1p[0], w0);
            cur2[q] = pk_fma_bhi_s(y1p[0], w1, cur2[q]);
#pragma unroll
            for (int p8 = 1; p8 < 8; ++p8) {
                float2 wl = *(const float2*)(W1p + 384 + (2*p8)*8 + 2*q);
                float2 wh = *(const float2*)(W1p + 384 + (2*p8+1)*8 + 2*q);
                cur2[q] = pk_fma_blo_s(y1p[p8], wl, cur2[q]);
                cur2[q] = pk_fma_bhi_s(y1p[p8], wh, cur2[q]);
            }
        }
        // z2
        {
            float2 w0 = *(const float2*)(W1p + 256 + 2*q);
            float2 w1 = *(const float2*)(W1p + 256 + 8 + 2*q);
            zk2[q] = pk_mul_blo_s(y1p[0], w0);
            zk2[q] = pk_fma_bhi_s(y1p[0], w1, zk2[q]);
#pragma unroll
            for (int p8 = 1; p8 < 8; ++p8) {
                float2 wl = *(const float2*)(W1p + 256 + (2*p8)*8 + 2*q);
                float2 wh = *(const float2*)(W1p + 256 + (2*p8+1)*8 + 2*q);
                zk2[q] = pk_fma_blo_s(y1p[p8], wl, zk2[q]);
                zk2[q] = pk_fma_bhi_s(y1p[p8], wh, zk2[q]);
            }
        }
        // z1
        {
            float2 w0 = *(const float2*)(W1p + 128 + 2*q);
            float2 w1 = *(const float2*)(W1p + 128 + 8 + 2*q);
            zk1[q] = pk_mul_blo_s(y1p[0], w0);
            zk1[q] = pk_fma_bhi_s(y1p[0], w1, zk1[q]);
#pragma unroll
            for (int p8 = 1; p8 < 8; ++p8) {
                float2 wl = *(const float2*)(W1p + 128 + (2*p8)*8 + 2*q);
                float2 wh = *(const float2*)(W1p + 128 + (2*p8+1)*8 + 2*q);
                zk1[q] = pk_fma_blo_s(y1p[p8], wl, zk1[q]);
                zk1[q] = pk_fma_bhi_s(y1p[p8], wh, zk1[q]);
            }
        }
        // z0
        {
            float2 w0 = *(const float2*)(W1p + 2*q);
            float2 w1 = *(const float2*)(W1p + 8 + 2*q);
            zk0[q] = pk_mul_blo_s(y1p[0], w0);
            zk0[q] = pk_fma_bhi_s(y1p[0], w1, zk0[q]);
#pragma unroll
            for (int p8 = 1; p8 < 8; ++p8) {
                float2 wl = *(const float2*)(W1p + (2*p8)*8 + 2*q);
                float2 wh = *(const float2*)(W1p + (2*p8+1)*8 + 2*q);
                zk0[q] = pk_fma_blo_s(y1p[p8], wl, zk0[q]);
                zk0[q] = pk_fma_bhi_s(y1p[p8], wh, zk0[q]);
            }
        }
    }
    // Lean Horner loop: agg + 4 packed adds per hop — no projection on the barrier path.
#pragma unroll
    for (int kh = 2; kh >= 0; --kh) {
        *(float4*)(slab + n * 12)     = make_float4(cur2[0].x, cur2[0].y, cur2[1].x, cur2[1].y);
        *(float4*)(slab + n * 12 + 4) = make_float4(cur2[2].x, cur2[2].y, cur2[3].x, cur2[3].y);
        WSYNC();
        float2 ag[4] = {zero2, zero2, zero2, zero2};
#pragma unroll
        for (int m = 0; m < 10; ++m) {
            const float4 p = *(const float4*)(slab + m * 12);
            const float4 r = *(const float4*)(slab + m * 12 + 4);
            const float2 pa = make_float2(p.x, p.y), pb = make_float2(p.z, p.w);
            const float2 ra = make_float2(r.x, r.y), rb = make_float2(r.z, r.w);
            const float2 am = arow2[m >> 1];
            if ((m & 1) == 0) {
                ag[0] = pk_fma_blo(am, pa, ag[0]);
                ag[1] = pk_fma_blo(am, pb, ag[1]);
                ag[2] = pk_fma_blo(am, ra, ag[2]);
                ag[3] = pk_fma_blo(am, rb, ag[3]);
            } else {
                ag[0] = pk_fma_bhi(am, pa, ag[0]);
                ag[1] = pk_fma_bhi(am, pb, ag[1]);
                ag[2] = pk_fma_bhi(am, ra, ag[2]);
                ag[3] = pk_fma_bhi(am, rb, ag[3]);
            }
        }
        WSYNC();
#pragma unroll
        for (int q = 0; q < 4; ++q) {
            const float2 zq = (kh == 2) ? zk2[q] : (kh == 1) ? zk1[q] : zk0[q];
            cur2[q] = pk_add2(zq, ag[q]);
        }
    }
    float2 y2p[4];
#pragma unroll
    for (int q = 0; q < 4; ++q) {
        float2 b2 = *(const float2*)(b1p + 2*q);
        y2p[q] = leaky2(pk_add_vs(cur2[q], b2));
    }

    // ================= heads =================
    *(float4*)(slab + n * 12)     = make_float4(y2p[0].x, y2p[0].y, y2p[1].x, y2p[1].y);
    *(float4*)(slab + n * 12 + 4) = make_float4(y2p[2].x, y2p[2].y, y2p[3].x, y2p[3].y);

    float2 accA = zero2, accT = zero2;
#pragma unroll
    for (int q = 0; q < 4; ++q) {
        float2 bp2 = *(const float2*)(bpp + 2*q);
        float2 cp2 = *(const float2*)(cpp + 2*q);
        accA = pk_fma_vs(y2p[q], bp2, accA);
        accT = pk_fma_vs(y2p[q], cp2, accT);
    }
    const float ay = accA.x + accA.y;
    const float ty = accT.x + accT.y;
    if (valid)
        out[OFF_AIK + (size_t)g * 10 + n] = a0v + fmaxf(ay, 0.f);

    float tk = ty * (1.f - fmaxf(x2, 0.f));
    if (tk == 0.f) tk = -1e10f;
    const float tks = tk * LOG2E;     // exp2-scaled logit

    float2 yw2[4];
#pragma unroll
    for (int qd = 0; qd < 4; ++qd) {
        float2 aA = zero2, aB = zero2;
#pragma unroll
        for (int q = 0; q < 4; ++q) {
            float2 wA = *(const float2*)(wwp + (2*qd)*8 + 2*q);
            float2 wB = *(const float2*)(wwp + (2*qd+1)*8 + 2*q);
            aA = pk_fma_vs(y2p[q], wA, aA);
            aB = pk_fma_vs(y2p[q], wB, aB);
        }
        yw2[qd] = make_float2(aA.x + aA.y, aB.x + aB.y);
    }
    WSYNC();   // y2 rows visible
    float kyr[10];
#pragma unroll
    for (int m = 0; m < 10; ++m) {
        const float4 p = *(const float4*)(slab + m * 12);
        const float4 r = *(const float4*)(slab + m * 12 + 4);
        float2 acc = pk_mul2(yw2[0], make_float2(p.x, p.y));
        acc = pk_fma2(yw2[1], make_float2(p.z, p.w), acc);
        acc = pk_fma2(yw2[2], make_float2(r.x, r.y), acc);
        acc = pk_fma2(yw2[3], make_float2(r.z, r.w), acc);
        kyr[m] = (acc.x + acc.y) * LOG2E;   // exp2-scaled
    }
    WSYNC();   // all y2 reads done; region reusable for ky (stride 10)
#pragma unroll
    for (int q = 0; q < 5; ++q)
        *(float2*)(slab + n * 10 + 2*q) = make_float2(kyr[2*q], kyr[2*q+1]);
    slab[120 + n] = tks;

    __syncthreads();   // the ONE cross-wave barrier

    // ---- t softmax over K (exp2 domain, exp-reuse) ----
    {
        const float tv0 = sm[(0*GPW + s)*SLAB + 120 + n];
        const float tv1 = sm[(1*GPW + s)*SLAB + 120 + n];
        const float tv2 = sm[(2*GPW + s)*SLAB + 120 + n];
        const float tv3 = sm[(3*GPW + s)*SLAB + 120 + n];
        const float mx = fmaxf(fmaxf(tv0, tv1), fmaxf(tv2, tv3));
        const float e0 = fexp2(tv0-mx), e1 = fexp2(tv1-mx);
        const float e2 = fexp2(tv2-mx), e3 = fexp2(tv3-mx);
        const float den = e0 + e1 + e2 + e3;
        const float own = (w == 0) ? e0 : (w == 1) ? e1 : (w == 2) ? e2 : e3;
        if (valid)
            out[OFF_TJ + (size_t)g * 10 + n] = own * rcpf(den);
    }
    // ---- k_ij softmax over K (exp2 domain, exp-reuse) ----
    {
        const float* k0 = sm + (0*GPW + s)*SLAB + n * 10;
        const float* k1 = sm + (1*GPW + s)*SLAB + n * 10;
        const float* k2 = sm + (2*GPW + s)*SLAB + n * 10;
        const float* k3 = sm + (3*GPW + s)*SLAB + n * 10;
        float* po = out + (size_t)g * 100 + n * 10;
#pragma unroll
        for (int q = 0; q < 5; ++q) {
            const float2 a = *(const float2*)(k0 + 2*q);
            const float2 b = *(const float2*)(k1 + 2*q);
            const float2 c = *(const float2*)(k2 + 2*q);
            const float2 d = *(const float2*)(k3 + 2*q);
            const float2 mx2v = el_max2(el_max2(a, b), el_max2(c, d));
            const float eax = fexp2(a.x-mx2v.x), ebx = fexp2(b.x-mx2v.x);
            const float ecx = fexp2(c.x-mx2v.x), edx = fexp2(d.x-mx2v.x);
            const float eay = fexp2(a.y-mx2v.y), eby = fexp2(b.y-mx2v.y);
            const float ecy = fexp2(c.y-mx2v.y), edy = fexp2(d.y-mx2v.y);
            const float dl = eax + ebx + ecx + edx;
            const float dh = eay + eby + ecy + edy;
            const float ox = (w == 0) ? eax : (w == 1) ? ebx : (w == 2) ? ecx : edx;
            const float oy = (w == 0) ? eay : (w == 1) ? eby : (w == 2) ? ecy : edy;
            if (valid)
                ((float2*)po)[q] = make_float2(ox * rcpf(dl), oy * rcpf(dh));
        }
    }
}

extern "C" void kernel_launch(void* const* d_in, const int* in_sizes, int n_in,
                              void* d_out, int out_size, void* d_ws, size_t ws_size,
                              hipStream_t stream) {
    const float* x   = (const float*)d_in[0];
    // d_in[1] = edge_index: deterministic pattern, never read
    const float* ew  = (const float*)d_in[2];
    const float* eig = (const float*)d_in[6];
    const float* a0  = (const float*)d_in[7];
    const float* W0  = (const float*)d_in[8];
    const float* b0  = (const float*)d_in[9];
    const float* W1  = (const float*)d_in[10];
    const float* b1  = (const float*)d_in[11];
    const float* bpw = (const float*)d_in[12];
    const float* cpw = (const float*)d_in[13];
    const float* www = (const float*)d_in[14];
    float* out = (float*)d_out;

    const int grid = (BATCH + GPW - 1) / GPW;   // 5462
    gnn_fused<<<dim3(grid), dim3(NTHREADS), 0, stream>>>(
        x, ew, eig, a0, W0, b0, W1, b1, bpw, cpw, www, out);
}